// Round 2
// baseline (3115.050 us; speedup 1.0000x reference)
//
#include <hip/hip_runtime.h>

// ---- problem constants (match reference shape_source) ----
constexpr int B   = 8;
constexpr int N0  = 50000;
constexpr int N1  = 12500;
constexpr int E   = 400000;
constexpr int FIN = 3;
constexpr int C   = 32;
constexpr int Z   = 128;
constexpr int M   = N1 * C;        // 400000
constexpr int DOWN_NNZ = N1 * 4;
constexpr int UP_NNZ   = N0 * 3;

// ---------------- CSR build (over dst!) ----------------
__global__ void k_hist(const int* __restrict__ dst, int* __restrict__ cnt) {
    int e = blockIdx.x * 256 + threadIdx.x;
    if (e < E) atomicAdd(&cnt[dst[e]], 1);
}

// exclusive scan of cnt into rp (chunked), chunk sums into part
__global__ void k_scan_chunk(const int* __restrict__ cnt, int* __restrict__ rp,
                             int* __restrict__ part) {
    __shared__ int s[512];
    int t = threadIdx.x;
    int i = blockIdx.x * 512 + t;
    int v = (i < N0) ? cnt[i] : 0;
    s[t] = v;
    __syncthreads();
    for (int off = 1; off < 512; off <<= 1) {
        int add = (t >= off) ? s[t - off] : 0;
        __syncthreads();
        s[t] += add;
        __syncthreads();
    }
    if (i < N0) rp[i] = s[t] - v;     // exclusive within chunk
    if (t == 511) part[blockIdx.x] = s[511];
}

__global__ void k_scan_part(int* part, int nb) {
    if (threadIdx.x == 0 && blockIdx.x == 0) {
        int run = 0;
        for (int c = 0; c < nb; c++) { int t = part[c]; part[c] = run; run += t; }
    }
}

// rp += part (in place), also copy to pos; set rp[N0]=E
__global__ void k_scan_add(const int* __restrict__ part, int* __restrict__ rp,
                           int* __restrict__ pos) {
    int i = blockIdx.x * 256 + threadIdx.x;
    if (i < N0) {
        int r = rp[i] + part[i >> 9];
        rp[i] = r; pos[i] = r;
        if (i == 0) rp[N0] = E;
    }
}

__global__ void k_scatter(const int* __restrict__ ei, const float* __restrict__ norm,
                          int* __restrict__ pos, int* __restrict__ col_s,
                          float* __restrict__ val_s) {
    int e = blockIdx.x * 256 + threadIdx.x;
    if (e < E) {
        int d = ei[E + e];                 // dst row
        int j = atomicAdd(&pos[d], 1);
        col_s[j] = ei[e];                  // src
        val_s[j] = norm[e];
    }
}

// ---------------- 3-channel propagate (encoder Chebyshev) ----------------
template <bool HAS_SUB>
__global__ void k_prop3(const int* __restrict__ rp, const int* __restrict__ col,
                        const float* __restrict__ val, const float* __restrict__ src,
                        const float* __restrict__ sub, float* __restrict__ out) {
    int n = blockIdx.x * 256 + threadIdx.x;
    if (n >= N0) return;
    int b = blockIdx.y;
    const float* sb = src + (size_t)b * N0 * 3;
    int s = rp[n], e = rp[n + 1];
    float a0 = 0.f, a1 = 0.f, a2 = 0.f;
    for (int j = s; j < e; j++) {
        int sc = col[j]; float w = val[j];
        a0 += w * sb[(size_t)sc * 3 + 0];
        a1 += w * sb[(size_t)sc * 3 + 1];
        a2 += w * sb[(size_t)sc * 3 + 2];
    }
    size_t o = ((size_t)b * N0 + n) * 3;
    if (HAS_SUB) {
        a0 = 2.f * a0 - sub[o + 0];
        a1 = 2.f * a1 - sub[o + 1];
        a2 = 2.f * a2 - sub[o + 2];
    }
    out[o + 0] = a0; out[o + 1] = a1; out[o + 2] = a2;
}

// encoder combine: h = relu(b + sum_k T_k @ W_k), Cin=3, Cout=32
__global__ void k_enc_combine(const float* __restrict__ x,
                              const float* __restrict__ T1, const float* __restrict__ T2,
                              const float* __restrict__ T3, const float* __restrict__ T4,
                              const float* __restrict__ T5,
                              const float* __restrict__ W, const float* __restrict__ bias,
                              float* __restrict__ out) {
    int o = threadIdx.x & 31, nl = threadIdx.x >> 5;
    int n = blockIdx.x * 8 + nl;           // grid.x = N0/8 exactly
    int b = blockIdx.y;
    size_t b3 = ((size_t)b * N0 + n) * 3;
    const float* Ts[6] = { x, T1, T2, T3, T4, T5 };
    float t[18];
#pragma unroll
    for (int k = 0; k < 6; k++) {
        t[k * 3 + 0] = Ts[k][b3 + 0];
        t[k * 3 + 1] = Ts[k][b3 + 1];
        t[k * 3 + 2] = Ts[k][b3 + 2];
    }
    float acc = bias[o];
#pragma unroll
    for (int q = 0; q < 18; q++) acc += t[q] * W[q * 32 + o];
    out[((size_t)b * N0 + n) * 32 + o] = fmaxf(acc, 0.f);
}

// ---------------- pools (fixed degree, no atomics) ----------------
__global__ void k_pool4(const int* __restrict__ dcol, const float* __restrict__ dval,
                        const float* __restrict__ src, float* __restrict__ out) {
    int c = threadIdx.x & 31, rl = threadIdx.x >> 5;
    int r = blockIdx.x * 8 + rl;
    if (r >= N1) return;
    int b = blockIdx.y;
    const float* sb = src + (size_t)b * N0 * 32;
    float a = 0.f;
#pragma unroll
    for (int t = 0; t < 4; t++) {
        int idx = 4 * r + t;
        a += dval[idx] * sb[(size_t)dcol[idx] * 32 + c];
    }
    out[((size_t)b * N1 + r) * 32 + c] = a;
}

__global__ void k_pool3(const int* __restrict__ ucol, const float* __restrict__ uval,
                        const float* __restrict__ src, float* __restrict__ out) {
    int c = threadIdx.x & 31, rl = threadIdx.x >> 5;
    int i = blockIdx.x * 8 + rl;           // grid.x = N0/8 exactly
    int b = blockIdx.y;
    const float* sb = src + (size_t)b * N1 * 32;
    float a = 0.f;
#pragma unroll
    for (int t = 0; t < 3; t++) {
        int idx = 3 * i + t;
        a += uval[idx] * sb[(size_t)ucol[idx] * 32 + c];
    }
    out[((size_t)b * N0 + i) * 32 + c] = a;
}

// ---------------- dense linears ----------------
__global__ void k_zinit(const float* __restrict__ bz, float* __restrict__ z) {
    int t = blockIdx.x * 256 + threadIdx.x;
    if (t < B * Z) z[t] = bz[t & (Z - 1)];
}

__global__ void k_enclin(const float* __restrict__ S0, const float* __restrict__ W,
                         float* __restrict__ z) {
    int zl = threadIdx.x & 127, half = threadIdx.x >> 7;
    int chunk = (M + gridDim.x - 1) / gridDim.x;
    int m0 = blockIdx.x * chunk;
    int m1 = min(m0 + chunk, M);
    float acc[B];
#pragma unroll
    for (int b = 0; b < B; b++) acc[b] = 0.f;
    for (int m = m0 + half; m < m1; m += 2) {
        float w = W[(size_t)m * Z + zl];
#pragma unroll
        for (int b = 0; b < B; b++) acc[b] += S0[(size_t)b * M + m] * w;
    }
    __shared__ float red[128 * B];
    if (half == 1) {
#pragma unroll
        for (int b = 0; b < B; b++) red[zl * B + b] = acc[b];
    }
    __syncthreads();
    if (half == 0) {
#pragma unroll
        for (int b = 0; b < B; b++) atomicAdd(&z[b * Z + zl], acc[b] + red[zl * B + b]);
    }
}

__global__ void k_declin(const float* __restrict__ z, const float* __restrict__ W,
                         const float* __restrict__ bias, float* __restrict__ out) {
    __shared__ float zs[B * Z];
    for (int i = threadIdx.x; i < B * Z; i += 256) zs[i] = z[i];
    __syncthreads();
    int m = blockIdx.x * 256 + threadIdx.x;
    if (m >= M) return;
    float bv = bias[m];
    float acc[B];
#pragma unroll
    for (int b = 0; b < B; b++) acc[b] = bv;
    for (int j = 0; j < Z; j++) {
        float w = W[(size_t)j * M + m];
#pragma unroll
        for (int b = 0; b < B; b++) acc[b] += zs[b * Z + j] * w;
    }
#pragma unroll
    for (int b = 0; b < B; b++) out[(size_t)b * M + m] = fmaxf(acc[b], 0.f);
}

// ---------------- conv k=0 init: out = [bias +] (relu?)in @ W ----------------
template <int COUT, bool RELU_IN>
__global__ void k_conv_init(const float* __restrict__ in, const float* __restrict__ W,
                            const float* __restrict__ bias, float* __restrict__ out) {
    int lane = threadIdx.x & 31, nl = threadIdx.x >> 5;
    int n = blockIdx.x * 8 + nl;           // grid.x = N0/8 exactly (full waves for shfl)
    int b = blockIdx.y;
    size_t base = ((size_t)b * N0 + n) * 32;
    float t = in[base + lane];
    if (RELU_IN) t = fmaxf(t, 0.f);
    if (COUT == 32) {
        float Wr[32];
#pragma unroll
        for (int cc = 0; cc < 32; cc++) Wr[cc] = W[cc * 32 + lane];
        float acc = bias ? bias[lane] : 0.f;
#pragma unroll
        for (int cc = 0; cc < 32; cc++) acc += __shfl(t, cc, 32) * Wr[cc];
        out[base + lane] = acc;
    } else {
        float p0 = t * W[lane * 3 + 0];
        float p1 = t * W[lane * 3 + 1];
        float p2 = t * W[lane * 3 + 2];
#pragma unroll
        for (int msk = 16; msk >= 1; msk >>= 1) {
            p0 += __shfl_xor(p0, msk, 32);
            p1 += __shfl_xor(p1, msk, 32);
            p2 += __shfl_xor(p2, msk, 32);
        }
        if (lane == 0) {
            size_t ob = ((size_t)b * N0 + n) * 3;
            out[ob + 0] = p0; out[ob + 1] = p1; out[ob + 2] = p2;
        }
    }
}

// ---------------- fused propagate + Chebyshev update + acc += Tx @ W ----------------
template <int COUT, bool HAS_SUB, bool RELU_SRC, bool RELU_SUB>
__global__ void k_prop_fused(const int* __restrict__ rp, const int* __restrict__ col,
                             const float* __restrict__ val, const float* __restrict__ src,
                             const float* __restrict__ sub, float* __restrict__ txout,
                             const float* __restrict__ W, float* __restrict__ acc) {
    int lane = threadIdx.x & 31, nl = threadIdx.x >> 5;
    int n = blockIdx.x * 8 + nl;           // grid.x = N0/8 exactly
    int b = blockIdx.y;
    const float* sb = src + (size_t)b * N0 * 32;
    int s = rp[n], e = rp[n + 1];
    float a = 0.f;
    for (int j = s; j < e; j++) {
        int sc = col[j]; float w = val[j];
        float v = sb[(size_t)sc * 32 + lane];
        if (RELU_SRC) v = fmaxf(v, 0.f);
        a += w * v;
    }
    size_t base = ((size_t)b * N0 + n) * 32;
    float t = a;
    if (HAS_SUB) {
        float sv = sub[base + lane];
        if (RELU_SUB) sv = fmaxf(sv, 0.f);
        t = 2.f * a - sv;
    }
    txout[base + lane] = t;
    if (COUT == 32) {
        float Wr[32];
#pragma unroll
        for (int cc = 0; cc < 32; cc++) Wr[cc] = W[cc * 32 + lane];
        float o = 0.f;
#pragma unroll
        for (int cc = 0; cc < 32; cc++) o += __shfl(t, cc, 32) * Wr[cc];
        acc[base + lane] += o;
    } else {
        float p0 = t * W[lane * 3 + 0];
        float p1 = t * W[lane * 3 + 1];
        float p2 = t * W[lane * 3 + 2];
#pragma unroll
        for (int msk = 16; msk >= 1; msk >>= 1) {
            p0 += __shfl_xor(p0, msk, 32);
            p1 += __shfl_xor(p1, msk, 32);
            p2 += __shfl_xor(p2, msk, 32);
        }
        if (lane == 0) {
            size_t ob = ((size_t)b * N0 + n) * 3;
            acc[ob + 0] += p0; acc[ob + 1] += p1; acc[ob + 2] += p2;
        }
    }
}

// ---------------- launch ----------------
extern "C" void kernel_launch(void* const* d_in, const int* in_sizes, int n_in,
                              void* d_out, int out_size, void* d_ws, size_t ws_size,
                              hipStream_t stream) {
    const float* x        = (const float*)d_in[0];
    const int*   ei       = (const int*)d_in[1];
    const float* A_norm   = (const float*)d_in[2];
    const int*   down_idx = (const int*)d_in[3];
    const float* down_val = (const float*)d_in[4];
    const int*   up_idx   = (const int*)d_in[5];
    const float* up_val   = (const float*)d_in[6];
    const float* W_enc0   = (const float*)d_in[7];
    const float* b_enc0   = (const float*)d_in[8];
    const float* W_dec0   = (const float*)d_in[9];
    const float* b_dec0   = (const float*)d_in[10];
    const float* W_dec1   = (const float*)d_in[11];
    const float* enc_lin_W = (const float*)d_in[12];
    const float* enc_lin_b = (const float*)d_in[13];
    const float* dec_lin_W = (const float*)d_in[14];
    const float* dec_lin_b = (const float*)d_in[15];
    float* OUT = (float*)d_out;

    // ws carve-up, 256B-aligned. Peak ≈ 157 MB.
    char* w8 = (char*)d_ws;
    auto alignup = [](size_t v) { return (v + 255) & ~(size_t)255; };
    size_t off = 0;
    auto carve = [&](size_t bytes) { void* p = w8 + off; off = alignup(off + bytes); return p; };

    int*   row_ptr = (int*)carve((size_t)(N0 + 1) * 4);
    int*   poscnt  = (int*)carve((size_t)N0 * 4);        // cnt during hist, pos during scatter
    int*   part    = (int*)carve(128 * 4);
    int*   col_s   = (int*)carve((size_t)E * 4);
    float* val_s   = (float*)carve((size_t)E * 4);
    float* zbuf    = (float*)carve((size_t)B * Z * 4);
    constexpr size_t BIG = (size_t)B * N0 * C;            // 12.8M floats = 51.2 MB
    float* A1 = (float*)carve(BIG * 4);
    float* A2 = (float*)carve(BIG * 4);
    float* A3 = (float*)carve(BIG * 4);
    (void)ws_size; (void)n_in; (void)in_sizes; (void)out_size;

    // aliases (lifetime-checked):
    float* T1 = A1 + 0 * (size_t)B * N0 * 3;   // encoder T1..T5 (24 MB in A1)
    float* T2 = A1 + 1 * (size_t)B * N0 * 3;
    float* T3 = A1 + 2 * (size_t)B * N0 * 3;
    float* T4 = A1 + 3 * (size_t)B * N0 * 3;
    float* T5 = A1 + 4 * (size_t)B * N0 * 3;
    float* HENC = A2;                          // encoder conv output
    float* S0   = A3;                          // pooled [B, M] (12.8 MB)
    float* S1   = A1;                          // decoder linear out [B, M] (T1..T5 dead)
    float* HUP  = A2;                          // up-pooled (HENC dead)
    float* ACC  = A3;                          // dec0 accumulator (S0 dead)

    const int* dcol = down_idx + DOWN_NNZ;
    const int* ucol = up_idx + UP_NNZ;

    dim3 blk(256);
    dim3 gE((E + 255) / 256);
    dim3 gN0t((N0 + 255) / 256);
    dim3 g3(gN0t.x, B);
    dim3 gN(N0 / 8, B);              // 6250, exact
    dim3 gP4((N1 + 7) / 8, B);
    dim3 gP3(N0 / 8, B);

    // ---- CSR build over dst ----
    hipMemsetAsync(poscnt, 0, (size_t)N0 * 4, stream);
    k_hist<<<gE, blk, 0, stream>>>(ei + E, poscnt);              // FIX: histogram DST
    int nchunks = (N0 + 511) / 512;  // 98
    k_scan_chunk<<<nchunks, 512, 0, stream>>>(poscnt, row_ptr, part);
    k_scan_part<<<1, 1, 0, stream>>>(part, nchunks);
    k_scan_add<<<gN0t, blk, 0, stream>>>(part, row_ptr, poscnt); // poscnt now = pos
    k_scatter<<<gE, blk, 0, stream>>>(ei, A_norm, poscnt, col_s, val_s);

    // ---- encoder cheb (Cin=3): T1..T5, combine -> HENC ----
    k_prop3<false><<<g3, blk, 0, stream>>>(row_ptr, col_s, val_s, x, nullptr, T1);
    k_prop3<true ><<<g3, blk, 0, stream>>>(row_ptr, col_s, val_s, T1, x,  T2);
    k_prop3<true ><<<g3, blk, 0, stream>>>(row_ptr, col_s, val_s, T2, T1, T3);
    k_prop3<true ><<<g3, blk, 0, stream>>>(row_ptr, col_s, val_s, T3, T2, T4);
    k_prop3<true ><<<g3, blk, 0, stream>>>(row_ptr, col_s, val_s, T4, T3, T5);
    k_enc_combine<<<gN, blk, 0, stream>>>(x, T1, T2, T3, T4, T5, W_enc0, b_enc0, HENC);

    // ---- down pool: HENC -> S0 ----
    k_pool4<<<gP4, blk, 0, stream>>>(dcol, down_val, HENC, S0);

    // ---- enc linear: z = S0 @ enc_lin_W + b ----
    k_zinit<<<(B * Z + 255) / 256, blk, 0, stream>>>(enc_lin_b, zbuf);
    k_enclin<<<400, blk, 0, stream>>>(S0, enc_lin_W, zbuf);

    // ---- dec linear: S1 = relu(z @ dec_lin_W + b) ----
    k_declin<<<(M + 255) / 256, blk, 0, stream>>>(zbuf, dec_lin_W, dec_lin_b, S1);

    // ---- up pool: S1 -> HUP ----
    k_pool3<<<gP3, blk, 0, stream>>>(ucol, up_val, S1, HUP);

    // ---- dec0 cheb (32->32), fused acc into ACC(A3); Tx rotate A2<->A1 ----
    k_conv_init<32, false><<<gN, blk, 0, stream>>>(HUP, W_dec0, b_dec0, ACC);
    k_prop_fused<32, false, false, false><<<gN, blk, 0, stream>>>(row_ptr, col_s, val_s, A2, nullptr, A1, W_dec0 + 1 * C * C, ACC);
    k_prop_fused<32, true,  false, false><<<gN, blk, 0, stream>>>(row_ptr, col_s, val_s, A1, A2, A2, W_dec0 + 2 * C * C, ACC);
    k_prop_fused<32, true,  false, false><<<gN, blk, 0, stream>>>(row_ptr, col_s, val_s, A2, A1, A1, W_dec0 + 3 * C * C, ACC);
    k_prop_fused<32, true,  false, false><<<gN, blk, 0, stream>>>(row_ptr, col_s, val_s, A1, A2, A2, W_dec0 + 4 * C * C, ACC);
    k_prop_fused<32, true,  false, false><<<gN, blk, 0, stream>>>(row_ptr, col_s, val_s, A2, A1, A1, W_dec0 + 5 * C * C, ACC);

    // ---- dec1 cheb (32->3), h2 = relu(ACC=A3) applied on read; OUT accumulated ----
    k_conv_init<3, true><<<gN, blk, 0, stream>>>(A3, W_dec1, nullptr, OUT);
    k_prop_fused<3, false, true,  false><<<gN, blk, 0, stream>>>(row_ptr, col_s, val_s, A3, nullptr, A2, W_dec1 + 1 * C * FIN, OUT);
    k_prop_fused<3, true,  false, true ><<<gN, blk, 0, stream>>>(row_ptr, col_s, val_s, A2, A3, A3, W_dec1 + 2 * C * FIN, OUT);
    k_prop_fused<3, true,  false, false><<<gN, blk, 0, stream>>>(row_ptr, col_s, val_s, A3, A2, A2, W_dec1 + 3 * C * FIN, OUT);
    k_prop_fused<3, true,  false, false><<<gN, blk, 0, stream>>>(row_ptr, col_s, val_s, A2, A3, A3, W_dec1 + 4 * C * FIN, OUT);
    k_prop_fused<3, true,  false, false><<<gN, blk, 0, stream>>>(row_ptr, col_s, val_s, A3, A2, A2, W_dec1 + 5 * C * FIN, OUT);
}

// Round 3
// 1867.806 us; speedup vs baseline: 1.6678x; 1.6678x over previous
//
#include <hip/hip_runtime.h>

// ---- problem constants ----
constexpr int B   = 8;
constexpr int N0  = 50000;
constexpr int N1  = 12500;
constexpr int E   = 400000;
constexpr int FIN = 3;
constexpr int C   = 32;
constexpr int Z   = 128;
constexpr int M   = N1 * C;        // 400000
constexpr int DOWN_NNZ = N1 * 4;
constexpr int UP_NNZ   = N0 * 3;
constexpr size_t BN4 = (size_t)B * N0 * 4;   // padded 3-ch buffer stride (floats)

// ---------------- CSR build (over dst) ----------------
__global__ void k_hist(const int* __restrict__ dst, int* __restrict__ cnt) {
    int e = blockIdx.x * 256 + threadIdx.x;
    if (e < E) atomicAdd(&cnt[dst[e]], 1);
}

__global__ void k_scan_chunk(const int* __restrict__ cnt, int* __restrict__ rp,
                             int* __restrict__ part) {
    __shared__ int s[512];
    int t = threadIdx.x;
    int i = blockIdx.x * 512 + t;
    int v = (i < N0) ? cnt[i] : 0;
    s[t] = v;
    __syncthreads();
    for (int off = 1; off < 512; off <<= 1) {
        int add = (t >= off) ? s[t - off] : 0;
        __syncthreads();
        s[t] += add;
        __syncthreads();
    }
    if (i < N0) rp[i] = s[t] - v;
    if (t == 511) part[blockIdx.x] = s[511];
}

__global__ void k_scan_part(int* part, int nb) {
    if (threadIdx.x == 0 && blockIdx.x == 0) {
        int run = 0;
        for (int c = 0; c < nb; c++) { int t = part[c]; part[c] = run; run += t; }
    }
}

__global__ void k_scan_add(const int* __restrict__ part, int* __restrict__ rp,
                           int* __restrict__ pos) {
    int i = blockIdx.x * 256 + threadIdx.x;
    if (i < N0) {
        int r = rp[i] + part[i >> 9];
        rp[i] = r; pos[i] = r;
        if (i == 0) rp[N0] = E;
    }
}

__global__ void k_scatter(const int* __restrict__ ei, const float* __restrict__ norm,
                          int* __restrict__ pos, int* __restrict__ col_s,
                          float* __restrict__ val_s) {
    int e = blockIdx.x * 256 + threadIdx.x;
    if (e < E) {
        int d = ei[E + e];
        int j = atomicAdd(&pos[d], 1);
        col_s[j] = ei[e];
        val_s[j] = norm[e];
    }
}

// ---------------- generic 3-channel propagate ----------------
// out = [g] + (SCALE2?2:1)*prop(src) - [sub];  strides: SSTR/USTR/OSTR in {3,4}
template <int SSTR, int USTR, int OSTR, bool HAS_G, bool HAS_SUB, bool SCALE2>
__global__ void k_prop3g(const int* __restrict__ rp, const int* __restrict__ col,
                         const float* __restrict__ val, const float* __restrict__ src,
                         const float* __restrict__ g, const float* __restrict__ sub,
                         float* __restrict__ out) {
    int n = blockIdx.x * 256 + threadIdx.x;
    if (n >= N0) return;
    int b = blockIdx.y;
    const float* sb = src + (size_t)b * N0 * SSTR;
    int s = rp[n], e = rp[n + 1];
    float a0 = 0.f, a1 = 0.f, a2 = 0.f;
    for (int j = s; j < e; j++) {
        int sc = col[j]; float w = val[j];
        if (SSTR == 4) {
            float4 v = *(const float4*)(sb + (size_t)sc * 4);
            a0 += w * v.x; a1 += w * v.y; a2 += w * v.z;
        } else {
            const float* p = sb + (size_t)sc * 3;
            a0 += w * p[0]; a1 += w * p[1]; a2 += w * p[2];
        }
    }
    if (SCALE2) { a0 *= 2.f; a1 *= 2.f; a2 *= 2.f; }
    if (HAS_G) {
        const float* gp = g + ((size_t)b * N0 + n) * 4;
        a0 += gp[0]; a1 += gp[1]; a2 += gp[2];
    }
    if (HAS_SUB) {
        const float* up = sub + ((size_t)b * N0 + n) * USTR;
        a0 -= up[0]; a1 -= up[1]; a2 -= up[2];
    }
    if (OSTR == 4) {
        *(float4*)(out + ((size_t)b * N0 + n) * 4) = make_float4(a0, a1, a2, 0.f);
    } else {
        float* op = out + ((size_t)b * N0 + n) * 3;
        op[0] = a0; op[1] = a1; op[2] = a2;
    }
}

// encoder combine: h = relu(b + sum_k T_k @ W_k); x stride 3, T stride 4
__global__ void k_enc_combine(const float* __restrict__ x,
                              const float* __restrict__ T1, const float* __restrict__ T2,
                              const float* __restrict__ T3, const float* __restrict__ T4,
                              const float* __restrict__ T5,
                              const float* __restrict__ W, const float* __restrict__ bias,
                              float* __restrict__ out) {
    int o = threadIdx.x & 31, nl = threadIdx.x >> 5;
    int n = blockIdx.x * 8 + nl;
    int b = blockIdx.y;
    size_t b3 = ((size_t)b * N0 + n) * 3;
    size_t b4 = ((size_t)b * N0 + n) * 4;
    float t[18];
    t[0] = x[b3 + 0]; t[1] = x[b3 + 1]; t[2] = x[b3 + 2];
    const float* Ts[5] = { T1, T2, T3, T4, T5 };
#pragma unroll
    for (int k = 0; k < 5; k++) {
        t[3 + k * 3 + 0] = Ts[k][b4 + 0];
        t[3 + k * 3 + 1] = Ts[k][b4 + 1];
        t[3 + k * 3 + 2] = Ts[k][b4 + 2];
    }
    float acc = bias[o];
#pragma unroll
    for (int q = 0; q < 18; q++) acc += t[q] * W[q * 32 + o];
    out[((size_t)b * N0 + n) * 32 + o] = fmaxf(acc, 0.f);
}

// ---------------- pools ----------------
__global__ void k_pool4(const int* __restrict__ dcol, const float* __restrict__ dval,
                        const float* __restrict__ src, float* __restrict__ out) {
    int c = threadIdx.x & 31, rl = threadIdx.x >> 5;
    int r = blockIdx.x * 8 + rl;
    if (r >= N1) return;
    int b = blockIdx.y;
    const float* sb = src + (size_t)b * N0 * 32;
    float a = 0.f;
#pragma unroll
    for (int t = 0; t < 4; t++) {
        int idx = 4 * r + t;
        a += dval[idx] * sb[(size_t)dcol[idx] * 32 + c];
    }
    out[((size_t)b * N1 + r) * 32 + c] = a;
}

__global__ void k_pool3(const int* __restrict__ ucol, const float* __restrict__ uval,
                        const float* __restrict__ src, float* __restrict__ out) {
    int c = threadIdx.x & 31, rl = threadIdx.x >> 5;
    int i = blockIdx.x * 8 + rl;
    int b = blockIdx.y;
    const float* sb = src + (size_t)b * N1 * 32;
    float a = 0.f;
#pragma unroll
    for (int t = 0; t < 3; t++) {
        int idx = 3 * i + t;
        a += uval[idx] * sb[(size_t)ucol[idx] * 32 + c];
    }
    out[((size_t)b * N0 + i) * 32 + c] = a;
}

// ---------------- enc linear: split-K two stage ----------------
// stage 1: 3125 blocks, each handles 128 m-rows; partial[blk][b*128+zl]
__global__ void k_enclin1(const float* __restrict__ S0, const float* __restrict__ W,
                          float* __restrict__ partial) {
    int zl = threadIdx.x & 127, half = threadIdx.x >> 7;
    int m0 = blockIdx.x * 128;
    float acc[B];
#pragma unroll
    for (int b = 0; b < B; b++) acc[b] = 0.f;
    for (int i = 0; i < 64; i++) {
        int m = m0 + half + 2 * i;
        float w = W[(size_t)m * Z + zl];
#pragma unroll
        for (int b = 0; b < B; b++) acc[b] += S0[(size_t)b * M + m] * w;
    }
    __shared__ float red[128 * B];
    if (half == 1) {
#pragma unroll
        for (int b = 0; b < B; b++) red[zl * B + b] = acc[b];
    }
    __syncthreads();
    if (half == 0) {
#pragma unroll
        for (int b = 0; b < B; b++)
            partial[(size_t)blockIdx.x * 1024 + b * 128 + zl] = acc[b] + red[zl * B + b];
    }
}

__global__ void k_enclin2(const float* __restrict__ partial, const float* __restrict__ bias,
                          float* __restrict__ z) {
    int i = blockIdx.x * 256 + threadIdx.x;
    if (i >= B * Z) return;
    float a = bias[i & 127];
    for (int k = 0; k < 3125; k++) a += partial[(size_t)k * 1024 + i];
    z[i] = a;
}

__global__ void k_declin(const float* __restrict__ z, const float* __restrict__ W,
                         const float* __restrict__ bias, float* __restrict__ out) {
    __shared__ float zs[B * Z];
    for (int i = threadIdx.x; i < B * Z; i += 256) zs[i] = z[i];
    __syncthreads();
    int m = blockIdx.x * 256 + threadIdx.x;
    if (m >= M) return;
    float bv = bias[m];
    float acc[B];
#pragma unroll
    for (int b = 0; b < B; b++) acc[b] = bv;
    for (int j = 0; j < Z; j++) {
        float w = W[(size_t)j * M + m];
#pragma unroll
        for (int b = 0; b < B; b++) acc[b] += zs[b * Z + j] * w;
    }
#pragma unroll
    for (int b = 0; b < B; b++) out[(size_t)b * M + m] = fmaxf(acc[b], 0.f);
}

// ---------------- dec0: 32->32 conv ----------------
__global__ void k_conv_init32(const float* __restrict__ in, const float* __restrict__ W,
                              const float* __restrict__ bias, float* __restrict__ out) {
    int lane = threadIdx.x & 31, nl = threadIdx.x >> 5;
    int n = blockIdx.x * 8 + nl;           // grid = N0/8 exactly
    float Wr[32];
#pragma unroll
    for (int cc = 0; cc < 32; cc++) Wr[cc] = W[cc * 32 + lane];
    float bv = bias[lane];
#pragma unroll
    for (int b = 0; b < B; b++) {
        size_t base = ((size_t)b * N0 + n) * 32;
        float t = in[base + lane];
        float acc = bv;
#pragma unroll
        for (int cc = 0; cc < 32; cc++) acc += __shfl(t, cc, 32) * Wr[cc];
        out[base + lane] = acc;
    }
}

template <bool HAS_SUB>
__global__ void k_prop_fused32(const int* __restrict__ rp, const int* __restrict__ col,
                               const float* __restrict__ val, const float* __restrict__ src,
                               const float* __restrict__ sub, float* __restrict__ txout,
                               const float* __restrict__ W, float* __restrict__ accb) {
    int lane = threadIdx.x & 31, nl = threadIdx.x >> 5;
    int n = blockIdx.x * 8 + nl;           // grid = N0/8 exactly
    int s = rp[n], e = rp[n + 1];
    float a[B];
#pragma unroll
    for (int b = 0; b < B; b++) a[b] = 0.f;
    for (int j = s; j < e; j++) {
        int sc = col[j]; float w = val[j];
        size_t sb = (size_t)sc * 32 + lane;
#pragma unroll
        for (int b = 0; b < B; b++) a[b] += w * src[(size_t)b * N0 * 32 + sb];
    }
    float Wr[32];
#pragma unroll
    for (int cc = 0; cc < 32; cc++) Wr[cc] = W[cc * 32 + lane];
#pragma unroll
    for (int b = 0; b < B; b++) {
        size_t base = ((size_t)b * N0 + n) * 32;
        float t = HAS_SUB ? 2.f * a[b] - sub[base + lane] : a[b];
        txout[base + lane] = t;
        float o = 0.f;
#pragma unroll
        for (int cc = 0; cc < 32; cc++) o += __shfl(t, cc, 32) * Wr[cc];
        accb[base + lane] += o;
    }
}

// ---------------- dec1: project h through all six 32->3 W_k ----------------
// G_k[b][n][0..2] (stride 4), k = lane/3, c = lane%3 for lane<18
__global__ void k_proj(const float* __restrict__ ACC, const float* __restrict__ W1,
                       float* __restrict__ G) {
    int lane = threadIdx.x & 31, nl = threadIdx.x >> 5;
    int n = blockIdx.x * 8 + nl;           // grid = N0/8 exactly
    int k = (lane < 18) ? lane / 3 : 0;
    int c = (lane < 18) ? lane % 3 : 0;
    float Wr[32];
#pragma unroll
    for (int cc = 0; cc < 32; cc++) Wr[cc] = W1[k * 96 + cc * 3 + c];
#pragma unroll
    for (int b = 0; b < B; b++) {
        float t = fmaxf(ACC[((size_t)b * N0 + n) * 32 + lane], 0.f);
        float o = 0.f;
#pragma unroll
        for (int cc = 0; cc < 32; cc++) o += __shfl(t, cc, 32) * Wr[cc];
        if (lane < 18) G[(size_t)k * BN4 + ((size_t)b * N0 + n) * 4 + c] = o;
    }
}

// ---------------- launch ----------------
extern "C" void kernel_launch(void* const* d_in, const int* in_sizes, int n_in,
                              void* d_out, int out_size, void* d_ws, size_t ws_size,
                              hipStream_t stream) {
    const float* x        = (const float*)d_in[0];
    const int*   ei       = (const int*)d_in[1];
    const float* A_norm   = (const float*)d_in[2];
    const int*   down_idx = (const int*)d_in[3];
    const float* down_val = (const float*)d_in[4];
    const int*   up_idx   = (const int*)d_in[5];
    const float* up_val   = (const float*)d_in[6];
    const float* W_enc0   = (const float*)d_in[7];
    const float* b_enc0   = (const float*)d_in[8];
    const float* W_dec0   = (const float*)d_in[9];
    const float* b_dec0   = (const float*)d_in[10];
    const float* W_dec1   = (const float*)d_in[11];
    const float* enc_lin_W = (const float*)d_in[12];
    const float* enc_lin_b = (const float*)d_in[13];
    const float* dec_lin_W = (const float*)d_in[14];
    const float* dec_lin_b = (const float*)d_in[15];
    float* OUT = (float*)d_out;

    char* w8 = (char*)d_ws;
    auto alignup = [](size_t v) { return (v + 255) & ~(size_t)255; };
    size_t off = 0;
    auto carve = [&](size_t bytes) { void* p = w8 + off; off = alignup(off + bytes); return p; };

    int*   row_ptr = (int*)carve((size_t)(N0 + 1) * 4);
    int*   poscnt  = (int*)carve((size_t)N0 * 4);
    int*   part    = (int*)carve(128 * 4);
    int*   col_s   = (int*)carve((size_t)E * 4);
    float* val_s   = (float*)carve((size_t)E * 4);
    float* zbuf    = (float*)carve((size_t)B * Z * 4);
    constexpr size_t BIG = (size_t)B * N0 * C;            // 12.8M floats
    float* A1 = (float*)carve(BIG * 4);
    float* A2 = (float*)carve(BIG * 4);
    float* A3 = (float*)carve(BIG * 4);
    (void)ws_size; (void)n_in; (void)in_sizes; (void)out_size;

    // aliases:
    float* T1 = A1 + 0 * BN4;   // padded encoder T buffers (32 MB in A1)
    float* T2 = A1 + 1 * BN4;
    float* T3 = A1 + 2 * BN4;
    float* T4 = A1 + 3 * BN4;
    float* T5 = A1 + 4 * BN4;
    float* HENC = A2;
    float* S0   = A3;
    float* PART = A2;           // enclin partials (12.8 MB), HENC dead by then
    float* S1   = A1;           // declin out [B,M]
    float* HUP  = A2;
    float* ACC  = A3;
    float* G    = A1;           // 6 x BN4 (38.4 MB) after dec0
    float* B4   = A2 + 0 * BN4; // Clenshaw b buffers
    float* B3   = A2 + 1 * BN4;
    float* B2   = A2 + 2 * BN4;
    float* B1   = A2 + 3 * BN4;

    const int* dcol = down_idx + DOWN_NNZ;
    const int* ucol = up_idx + UP_NNZ;

    dim3 blk(256);
    dim3 gE((E + 255) / 256);
    dim3 gN0t((N0 + 255) / 256);
    dim3 g3(gN0t.x, B);
    dim3 gN8(N0 / 8);                // 6250, exact
    dim3 gNB(N0 / 8, B);
    dim3 gP4((N1 + 7) / 8, B);
    dim3 gP3(N0 / 8, B);

    // ---- CSR build over dst ----
    hipMemsetAsync(poscnt, 0, (size_t)N0 * 4, stream);
    k_hist<<<gE, blk, 0, stream>>>(ei + E, poscnt);
    int nchunks = (N0 + 511) / 512;
    k_scan_chunk<<<nchunks, 512, 0, stream>>>(poscnt, row_ptr, part);
    k_scan_part<<<1, 1, 0, stream>>>(part, nchunks);
    k_scan_add<<<gN0t, blk, 0, stream>>>(part, row_ptr, poscnt);
    k_scatter<<<gE, blk, 0, stream>>>(ei, A_norm, poscnt, col_s, val_s);

    // ---- encoder cheb (Cin=3), padded T buffers ----
    k_prop3g<3,3,4,false,false,false><<<g3, blk, 0, stream>>>(row_ptr, col_s, val_s, x,  nullptr, nullptr, T1);
    k_prop3g<4,3,4,false,true, true ><<<g3, blk, 0, stream>>>(row_ptr, col_s, val_s, T1, nullptr, x,  T2);
    k_prop3g<4,4,4,false,true, true ><<<g3, blk, 0, stream>>>(row_ptr, col_s, val_s, T2, nullptr, T1, T3);
    k_prop3g<4,4,4,false,true, true ><<<g3, blk, 0, stream>>>(row_ptr, col_s, val_s, T3, nullptr, T2, T4);
    k_prop3g<4,4,4,false,true, true ><<<g3, blk, 0, stream>>>(row_ptr, col_s, val_s, T4, nullptr, T3, T5);
    k_enc_combine<<<gNB, blk, 0, stream>>>(x, T1, T2, T3, T4, T5, W_enc0, b_enc0, HENC);

    // ---- down pool ----
    k_pool4<<<gP4, blk, 0, stream>>>(dcol, down_val, HENC, S0);

    // ---- enc linear (split-K) ----
    k_enclin1<<<3125, blk, 0, stream>>>(S0, enc_lin_W, PART);
    k_enclin2<<<4, blk, 0, stream>>>(PART, enc_lin_b, zbuf);

    // ---- dec linear ----
    k_declin<<<(M + 255) / 256, blk, 0, stream>>>(zbuf, dec_lin_W, dec_lin_b, S1);

    // ---- up pool: S1 -> HUP ----
    k_pool3<<<gP3, blk, 0, stream>>>(ucol, up_val, S1, HUP);

    // ---- dec0 cheb (32->32), b-loop inside; rotate A2<->A1, ACC=A3 ----
    k_conv_init32<<<gN8, blk, 0, stream>>>(HUP, W_dec0, b_dec0, ACC);
    k_prop_fused32<false><<<gN8, blk, 0, stream>>>(row_ptr, col_s, val_s, A2, nullptr, A1, W_dec0 + 1 * C * C, ACC);
    k_prop_fused32<true ><<<gN8, blk, 0, stream>>>(row_ptr, col_s, val_s, A1, A2, A2, W_dec0 + 2 * C * C, ACC);
    k_prop_fused32<true ><<<gN8, blk, 0, stream>>>(row_ptr, col_s, val_s, A2, A1, A1, W_dec0 + 3 * C * C, ACC);
    k_prop_fused32<true ><<<gN8, blk, 0, stream>>>(row_ptr, col_s, val_s, A1, A2, A2, W_dec0 + 4 * C * C, ACC);
    k_prop_fused32<true ><<<gN8, blk, 0, stream>>>(row_ptr, col_s, val_s, A2, A1, A1, W_dec0 + 5 * C * C, ACC);

    // ---- dec1 via Clenshaw in 3-channel space ----
    // g_k = relu(ACC) @ W1_k  (6 projections)
    k_proj<<<gN8, blk, 0, stream>>>(ACC, W_dec1, G);
    float* G0 = G + 0 * BN4; float* G1 = G + 1 * BN4; float* G2 = G + 2 * BN4;
    float* G3c = G + 3 * BN4; float* G4 = G + 4 * BN4; float* G5 = G + 5 * BN4;
    // b5 = G5; b4 = G4 + 2L b5; b3 = G3 + 2L b4 - b5; b2..; b1..
    k_prop3g<4,4,4,true,false,true ><<<g3, blk, 0, stream>>>(row_ptr, col_s, val_s, G5, G4, nullptr, B4);
    k_prop3g<4,4,4,true,true, true ><<<g3, blk, 0, stream>>>(row_ptr, col_s, val_s, B4, G3c, G5, B3);
    k_prop3g<4,4,4,true,true, true ><<<g3, blk, 0, stream>>>(row_ptr, col_s, val_s, B3, G2, B4, B2);
    k_prop3g<4,4,4,true,true, true ><<<g3, blk, 0, stream>>>(row_ptr, col_s, val_s, B2, G1, B3, B1);
    // out = G0 + L b1 - b2   (scale 1)
    k_prop3g<4,4,3,true,true, false><<<g3, blk, 0, stream>>>(row_ptr, col_s, val_s, B1, G0, B2, OUT);
}